// Round 5
// baseline (2840.991 us; speedup 1.0000x reference)
//
#include <hip/hip_runtime.h>
#include <hip/hip_bf16.h>

// ---------------------------------------------------------------------------
// RPN pipeline:
//  1. conv3x3_v5: fp32 reg-tiled conv 2048->1024, K-split x4, partial sums,
//                 SOFTWARE-PIPELINED staging: chunk k+1's weights+features
//                 prefetched into registers while chunk k computes from LDS.
//  1b. reducex  : x = xp0+xp1+xp2+xp3 + bias (deterministic)
//  2. heads     : 1x1 convs (36 reg + 18 cls channels)  -> ho[2500][56]
//  3. decode    : box decode + clip + min-size filter   -> roi, sort keys
//  4. bitonic   : descending stable sort of 32768 64-bit keys
//  5. gather    : sorted boxes + valid flags
//  6. nmsmask   : 6000x6000 IoU suppression bitmask
//  7. nmsscan   : single-wave greedy scan (<=300 keeps) + write output
// ---------------------------------------------------------------------------

#define NPOS 2500
#define NBOX 22500
#define NSORT 32768
#define NPRE 6000
#define NWORDS 94
#define NPOST 300

// conv tiling
#define POST 256               // positions per block (padded-linear)
#define FWIN 362               // POST + 106 halo
#define FREG 364               // padded to multiple of 4 dwords
#define NSLOT 12               // ceil(8*FREG/256)
#define KSPLIT 4
#define CHUNKS 64              // (2048/KSPLIT)/8 ci-chunks per block

// ---------------- 1. conv 3x3, 2048 -> 1024, 50x50, pad 1 ------------------
// Lane roles (conflict-free LDS):
//   tp = tid&15 -> co (4 co each, Ws b128 @ tp*4: 64 consecutive dwords/wave)
//   g  = tid>>4 -> pos (16 pos each, Fs reads are 4-address broadcasts)
// Pipeline per chunk: sync / commit regs->LDS / sync / prefetch next chunk
// into regs (latency hides under compute) / compute.
__global__ __launch_bounds__(256, 3) void conv3x3_v5(
    const float* __restrict__ feat, const float* __restrict__ W1,
    float* __restrict__ xp) {
  __shared__ float Ws[72 * 64];      // 18,432 B  [kk][co]
  __shared__ float Fs[8 * FREG];     // 11,648 B  [ci][padded-linear window]
  const int tid = threadIdx.x;
  const int tp = tid & 15;
  const int g  = tid >> 4;
  const int q0 = blockIdx.x * POST;  // padded-linear tile base (11 tiles)
  const int co0 = blockIdx.y * 64;   // 16 co tiles
  const int bz = blockIdx.z;         // K-split 0..3 (512 ci each)

  // ---- precompute feature-staging global offsets (loop-invariant) ----
  int goffs[NSLOT];   // -1 => stage zero (border/pad), slot s = sl*256+tid
  #pragma unroll
  for (int sl = 0; sl < NSLOT; ++sl) {
    int s = sl * 256 + tid;
    int go = -1;
    if (s < 8 * FREG) {
      int ci = s / FREG, w = s - ci * FREG;
      int pl = q0 - 53 + w;
      if (w < FWIN && pl >= 0 && pl < 2704) {
        int r = pl / 52, cc = pl - r * 52;
        if (r >= 1 && r <= 50 && cc >= 1 && cc <= 50)
          go = ci * NPOS + (r - 1) * 50 + (cc - 1);
      }
    }
    goffs[sl] = go;
  }

  // ---- weight staging pointers: co-run tp*4..tp*4+3, kk = g + 16l ----
  const float* wp[4];
  #pragma unroll
  for (int c = 0; c < 4; ++c)
    wp[c] = W1 + (size_t)(co0 + tp * 4 + c) * 18432 + (size_t)(bz * 512) * 9 + g;
  const int nl = (g < 8) ? 5 : 4;    // kk = g+16l < 72 (wave-uniform)
  const float* fp = feat + (size_t)(bz * 512) * NPOS;

  float acc[4][16];
  #pragma unroll
  for (int c = 0; c < 4; ++c)
    #pragma unroll
    for (int j = 0; j < 16; ++j) acc[c][j] = 0.f;

  // ---- prefetch registers ----
  float wv[20];
  float fv[NSLOT];

  // initial prefetch (chunk 0)
  #pragma unroll
  for (int l = 0; l < 5; ++l) {
    if (l < nl) {
      #pragma unroll
      for (int c = 0; c < 4; ++c) wv[l * 4 + c] = wp[c][16 * l];
    }
  }
  #pragma unroll
  for (int sl = 0; sl < NSLOT; ++sl) {
    float v = 0.f;
    if (goffs[sl] >= 0) v = fp[goffs[sl]];
    fv[sl] = v;
  }

  for (int ch = 0; ch < CHUNKS; ++ch) {
    __syncthreads();
    // --- commit prefetched regs -> LDS (conflict-free) ---
    #pragma unroll
    for (int l = 0; l < 5; ++l) {
      if (l < nl) {
        float4 v;
        v.x = wv[l * 4 + 0];
        v.y = wv[l * 4 + 1];
        v.z = wv[l * 4 + 2];
        v.w = wv[l * 4 + 3];
        *(float4*)&Ws[(g + 16 * l) * 64 + tp * 4] = v;
      }
    }
    #pragma unroll
    for (int sl = 0; sl < NSLOT; ++sl) {
      int s = sl * 256 + tid;
      if (s < 8 * FREG) Fs[s] = fv[sl];
    }
    __syncthreads();

    // --- issue prefetch for next chunk (hides under compute below) ---
    if (ch + 1 < CHUNKS) {
      #pragma unroll
      for (int c = 0; c < 4; ++c) wp[c] += 72;
      fp += 8 * NPOS;
      #pragma unroll
      for (int l = 0; l < 5; ++l) {
        if (l < nl) {
          #pragma unroll
          for (int c = 0; c < 4; ++c) wv[l * 4 + c] = wp[c][16 * l];
        }
      }
      #pragma unroll
      for (int sl = 0; sl < NSLOT; ++sl) {
        float v = 0.f;
        if (goffs[sl] >= 0) v = fp[goffs[sl]];
        fv[sl] = v;
      }
    }

    // --- compute: per (ci,ky): 5 broadcast Fs reads + 3 Ws b128 / 192 FMA
    for (int ci = 0; ci < 8; ++ci) {
      #pragma unroll
      for (int ky = 0; ky < 3; ++ky) {
        const int fb = ci * FREG + ky * 52 + g * 16;
        float4 f0 = *(const float4*)&Fs[fb];
        float4 f1 = *(const float4*)&Fs[fb + 4];
        float4 f2 = *(const float4*)&Fs[fb + 8];
        float4 f3 = *(const float4*)&Fs[fb + 12];
        float2 f4 = *(const float2*)&Fs[fb + 16];
        float f[18] = {f0.x, f0.y, f0.z, f0.w, f1.x, f1.y, f1.z, f1.w,
                       f2.x, f2.y, f2.z, f2.w, f3.x, f3.y, f3.z, f3.w,
                       f4.x, f4.y};
        #pragma unroll
        for (int kx = 0; kx < 3; ++kx) {
          float4 w = *(const float4*)&Ws[(ci * 9 + ky * 3 + kx) * 64 + tp * 4];
          #pragma unroll
          for (int j = 0; j < 16; ++j) {
            acc[0][j] += w.x * f[j + kx];
            acc[1][j] += w.y * f[j + kx];
            acc[2][j] += w.z * f[j + kx];
            acc[3][j] += w.w * f[j + kx];
          }
        }
      }
    }
  }
  // --- write partial sums (plain stores) ---
  float* xpz = xp + (size_t)bz * (1024 * NPOS);
  #pragma unroll
  for (int j = 0; j < 16; ++j) {
    int pl = q0 + g * 16 + j;
    int r = pl / 52, cc = pl - r * 52;
    if (r >= 1 && r <= 50 && cc >= 1 && cc <= 50) {
      int p = (r - 1) * 50 + (cc - 1);
      #pragma unroll
      for (int c = 0; c < 4; ++c)
        xpz[(size_t)(co0 + tp * 4 + c) * NPOS + p] = acc[c][j];
    }
  }
}

// ---------------- 1b. reduce partials + bias -------------------------------
__global__ void reducex(const float* __restrict__ xp,
                        const float* __restrict__ b1, float* __restrict__ x) {
  int i = blockIdx.x * 256 + threadIdx.x;
  if (i >= 1024 * NPOS) return;
  const size_t S = (size_t)1024 * NPOS;
  float v = ((xp[i] + xp[i + S]) + (xp[i + 2 * S] + xp[i + 3 * S])) +
            b1[i / NPOS];
  x[i] = v;
}

// ---------------- 2. 1x1 conv heads (36 reg + 18 cls channels) -------------
__global__ __launch_bounds__(256) void heads(
    const float* __restrict__ x, const float* __restrict__ Wreg,
    const float* __restrict__ breg, const float* __restrict__ Wcls,
    const float* __restrict__ bcls, float* __restrict__ ho) {
  int p = blockIdx.x * 64 + threadIdx.x;
  int ch = blockIdx.y * 4 + threadIdx.y;
  if (p >= NPOS || ch >= 54) return;
  const float* w = (ch < 36) ? (Wreg + (size_t)ch * 1024)
                             : (Wcls + (size_t)(ch - 36) * 1024);
  float a0 = 0.f, a1 = 0.f, a2 = 0.f, a3 = 0.f;
  for (int c = 0; c < 1024; c += 4) {
    a0 += w[c + 0] * x[(size_t)(c + 0) * NPOS + p];
    a1 += w[c + 1] * x[(size_t)(c + 1) * NPOS + p];
    a2 += w[c + 2] * x[(size_t)(c + 2) * NPOS + p];
    a3 += w[c + 3] * x[(size_t)(c + 3) * NPOS + p];
  }
  float bias = (ch < 36) ? breg[ch] : bcls[ch - 36];
  ho[p * 56 + ch] = (a0 + a1) + (a2 + a3) + bias;
}

// ---------------- 3. decode + min-size filter + sort keys ------------------
__global__ void decodek(const float* __restrict__ ho,
                        const float* __restrict__ anchors,
                        float4* __restrict__ roi,
                        unsigned long long* __restrict__ keys) {
  int i = blockIdx.x * 256 + threadIdx.x;
  if (i >= NBOX) { keys[i] = 0ull; return; }
  int p = i / 9, a = i % 9;
  const float* hp = ho + p * 56;
  float dy = hp[a * 4 + 0], dx = hp[a * 4 + 1];
  float dh = hp[a * 4 + 2], dw = hp[a * 4 + 3];
  float s = hp[36 + a * 2 + 1];
  float ay1 = anchors[i * 4 + 0], ax1 = anchors[i * 4 + 1];
  float ay2 = anchors[i * 4 + 2], ax2 = anchors[i * 4 + 3];
  float ahh = ay2 - ay1, aww = ax2 - ax1;
  float acy = ay1 + 0.5f * ahh, acx = ax1 + 0.5f * aww;
  float cy = dy * ahh + acy, cx = dx * aww + acx;
  float h = expf(dh) * ahh, w = expf(dw) * aww;
  float y1 = fminf(fmaxf(cy - 0.5f * h, 0.f), 800.f);
  float x1 = fminf(fmaxf(cx - 0.5f * w, 0.f), 800.f);
  float y2 = fminf(fmaxf(cy + 0.5f * h, 0.f), 800.f);
  float x2 = fminf(fmaxf(cx + 0.5f * w, 0.f), 800.f);
  bool valid = ((y2 - y1) >= 16.f) && ((x2 - x1) >= 16.f);
  float sc = valid ? s : -__builtin_inff();
  unsigned u = __float_as_uint(sc);
  u = (u & 0x80000000u) ? ~u : (u | 0x80000000u);
  keys[i] = ((unsigned long long)u << 32) |
            (unsigned long long)(0xFFFFFFFFu - (unsigned)i);
  roi[i] = make_float4(y1, x1, y2, x2);
}

// ---------------- 4. bitonic sort (descending), 32768 keys -----------------
__global__ __launch_bounds__(1024) void bitonic_local(unsigned long long* keys) {
  __shared__ unsigned long long s[4096];
  int t = threadIdx.x;
  size_t base = (size_t)blockIdx.x * 4096;
  for (int m = t; m < 4096; m += 1024) s[m] = keys[base + m];
  __syncthreads();
  for (int k = 2; k <= 4096; k <<= 1) {
    for (int j = k >> 1; j > 0; j >>= 1) {
      for (int m = t; m < 4096; m += 1024) {
        int l = m ^ j;
        if (l > m) {
          bool desc = (((base + (size_t)m) & (size_t)k) == 0);
          unsigned long long a = s[m], b = s[l];
          if (desc ? (a < b) : (a > b)) { s[m] = b; s[l] = a; }
        }
      }
      __syncthreads();
    }
  }
  for (int m = t; m < 4096; m += 1024) keys[base + m] = s[m];
}

__global__ __launch_bounds__(1024) void bitonic_merge_local(
    unsigned long long* keys, int k) {
  __shared__ unsigned long long s[4096];
  int t = threadIdx.x;
  size_t base = (size_t)blockIdx.x * 4096;
  for (int m = t; m < 4096; m += 1024) s[m] = keys[base + m];
  __syncthreads();
  for (int j = 2048; j > 0; j >>= 1) {
    for (int m = t; m < 4096; m += 1024) {
      int l = m ^ j;
      if (l > m) {
        bool desc = (((base + (size_t)m) & (size_t)k) == 0);
        unsigned long long a = s[m], b = s[l];
        if (desc ? (a < b) : (a > b)) { s[m] = b; s[l] = a; }
      }
    }
    __syncthreads();
  }
  for (int m = t; m < 4096; m += 1024) keys[base + m] = s[m];
}

__global__ void bitonic_global(unsigned long long* keys, int k, int j) {
  int m = blockIdx.x * 256 + threadIdx.x;
  int l = m ^ j;
  if (l > m) {
    bool desc = ((m & k) == 0);
    unsigned long long a = keys[m], b = keys[l];
    if (desc ? (a < b) : (a > b)) { keys[m] = b; keys[l] = a; }
  }
}

// ---------------- 5. gather sorted top-6000 boxes + valid flags ------------
__global__ void gatherk(const unsigned long long* __restrict__ keys,
                        const float4* __restrict__ roi,
                        float4* __restrict__ sbox, int* __restrict__ validArr) {
  int t = blockIdx.x * 256 + threadIdx.x;
  if (t >= NPRE) return;
  unsigned long long k = keys[t];
  unsigned u = (unsigned)(k >> 32);
  int valid = (u > 0x007FFFFFu) ? 1 : 0;
  float4 b = make_float4(0.f, 0.f, 0.f, 0.f);
  if (valid) {
    int idx = (int)(0xFFFFFFFFu - (unsigned)(k & 0xFFFFFFFFull));
    b = roi[idx];
  }
  sbox[t] = b;
  validArr[t] = valid;
}

// ---------------- 6. NMS suppression bitmask -------------------------------
__global__ __launch_bounds__(64) void nmsmask(
    const float4* __restrict__ sbox, unsigned long long* __restrict__ mask) {
  int rb = blockIdx.x, cb = blockIdx.y;
  int t = threadIdx.x;
  __shared__ float4 cbx[64];
  __shared__ float car[64];
  int jj = cb * 64 + t;
  float4 c = (jj < NPRE) ? sbox[jj] : make_float4(0.f, 0.f, 0.f, 0.f);
  cbx[t] = c;
  car[t] = (c.w - c.y + 1.f) * (c.z - c.x + 1.f);
  __syncthreads();
  int i = rb * 64 + t;
  if (i >= NPRE) return;
  float4 b = sbox[i];
  float ai = (b.w - b.y + 1.f) * (b.z - b.x + 1.f);
  unsigned long long bits = 0ull;
  int nj = min(64, NPRE - cb * 64);
  for (int j = 0; j < nj; ++j) {
    float4 cc = cbx[j];
    float yy1 = fmaxf(b.x, cc.x), xx1 = fmaxf(b.y, cc.y);
    float yy2 = fminf(b.z, cc.z), xx2 = fminf(b.w, cc.w);
    float inter = fmaxf(xx2 - xx1 + 1.f, 0.f) * fmaxf(yy2 - yy1 + 1.f, 0.f);
    float iou = inter / (ai + car[j] - inter);
    if (iou > 0.7f) bits |= (1ull << j);
  }
  mask[(size_t)i * NWORDS + cb] = bits;
}

// ---------------- 7. greedy scan (single wave) + output --------------------
__global__ __launch_bounds__(64) void nmsscan(
    const unsigned long long* __restrict__ mask,
    const int* __restrict__ validArr, const float4* __restrict__ sbox,
    float* __restrict__ out) {
  int t = threadIdx.x;
  __shared__ unsigned long long remv[NWORDS];
  __shared__ int keepIdx[NPOST];
  remv[t] = 0ull;
  if (t + 64 < NWORDS) remv[t + 64] = 0ull;
  __syncthreads();
  int nk = 0;
  for (int wb = 0; wb < NWORDS && nk < NPOST; ++wb) {
    int gi = wb * 64 + t;
    bool v = (gi < NPRE) && (validArr[gi] != 0);
    unsigned long long avail = __ballot(v);
    avail &= ~remv[wb];
    while (avail != 0ull && nk < NPOST) {
      int b = __ffsll((unsigned long long)avail) - 1;
      int i = wb * 64 + b;
      if (t == 0) keepIdx[nk] = i;
      nk++;
      const unsigned long long* row = mask + (size_t)i * NWORDS;
      remv[t] |= row[t];
      if (t + 64 < NWORDS) remv[t + 64] |= row[t + 64];
      __syncthreads();
      avail &= ~remv[wb];
    }
  }
  __syncthreads();
  for (int r = t; r < NPOST; r += 64) {
    float4 bx = make_float4(0.f, 0.f, 0.f, 0.f);
    if (r < nk) bx = sbox[keepIdx[r]];
    reinterpret_cast<float4*>(out)[r] = bx;
  }
}

// ---------------------------------------------------------------------------
extern "C" void kernel_launch(void* const* d_in, const int* in_sizes, int n_in,
                              void* d_out, int out_size, void* d_ws,
                              size_t ws_size, hipStream_t stream) {
  const float* feat    = (const float*)d_in[0];
  const float* anchors = (const float*)d_in[1];
  const float* W1      = (const float*)d_in[2];
  const float* b1      = (const float*)d_in[3];
  const float* Wreg    = (const float*)d_in[4];
  const float* breg    = (const float*)d_in[5];
  const float* Wcls    = (const float*)d_in[6];
  const float* bcls    = (const float*)d_in[7];

  char* ws = (char*)d_ws;
  float* x                 = (float*)(ws);             // 10,240,000 B
  float* xp                = (float*)(ws + 10240000);  // 40,960,000 B (dead after reducex)
  // aliases inside xp (written strictly after reducex):
  float4* sbox             = (float4*)(ws + 10240000);          //     96,256 B
  int* validArr            = (int*)(ws + 10336256);             //     24,064 B
  unsigned long long* mask = (unsigned long long*)(ws + 10360320); // 4,524,032 B
  float* ho                = (float*)(ws + 51200000);  //    560,000 B
  float4* roi              = (float4*)(ws + 51760000); //    360,000 B
  unsigned long long* keys = (unsigned long long*)(ws + 52120000); // 262,144 B
  float* out = (float*)d_out;

  conv3x3_v5<<<dim3(11, 16, KSPLIT), 256, 0, stream>>>(feat, W1, xp);
  reducex<<<10000, 256, 0, stream>>>(xp, b1, x);
  heads<<<dim3(40, 14), dim3(64, 4), 0, stream>>>(x, Wreg, breg, Wcls, bcls, ho);
  decodek<<<128, 256, 0, stream>>>(ho, anchors, roi, keys);

  bitonic_local<<<8, 1024, 0, stream>>>(keys);
  for (int k = 8192; k <= NSORT; k <<= 1) {
    for (int j = k >> 1; j >= 4096; j >>= 1)
      bitonic_global<<<128, 256, 0, stream>>>(keys, k, j);
    bitonic_merge_local<<<8, 1024, 0, stream>>>(keys, k);
  }

  gatherk<<<24, 256, 0, stream>>>(keys, roi, sbox, validArr);
  nmsmask<<<dim3(NWORDS, NWORDS), 64, 0, stream>>>(sbox, mask);
  nmsscan<<<1, 64, 0, stream>>>(mask, validArr, sbox, out);
}

// Round 6
// 2224.360 us; speedup vs baseline: 1.2772x; 1.2772x over previous
//
#include <hip/hip_runtime.h>
#include <hip/hip_bf16.h>

// ---------------------------------------------------------------------------
// RPN pipeline:
//  0. initzero  : zero the gl_lds zero-source dword (aliases keys region)
//  1. conv3x3_v6: fp32 reg-tiled conv 2048->1024, K-split x4, partial sums.
//                 Double-buffered LDS; weights staged via short-lived reg
//                 round-trip; features staged via global_load_lds (async,
//                 zero registers, in flight across the whole compute body).
//                 One barrier per chunk. NO register state alive across
//                 compute (v5's spill bug).
//  1b. reducex  : x = xp0+xp1+xp2+xp3 + bias (deterministic)
//  2. heads     : 1x1 convs (36 reg + 18 cls channels)  -> ho[2500][56]
//  3. decode    : box decode + clip + min-size filter   -> roi, sort keys
//  4. bitonic   : descending stable sort of 32768 64-bit keys
//  5. gather    : sorted boxes + valid flags
//  6. nmsmask   : 6000x6000 IoU suppression bitmask
//  7. nmsscan   : single-wave greedy scan (<=300 keeps) + write output
// ---------------------------------------------------------------------------

#define NPOS 2500
#define NBOX 22500
#define NSORT 32768
#define NPRE 6000
#define NWORDS 94
#define NPOST 300

// conv tiling
#define POST 256               // positions per block (padded-linear)
#define FWIN 362               // POST + 106 halo
#define FREG 364               // padded row stride (dwords)
#define FSN  (8 * FREG)        // 2912 dwords per feature buffer
#define WSN  (72 * 64)         // 4608 dwords per weight buffer
#define NSLOT 12               // ceil(FSN/256)
#define KSPLIT 4
#define CHUNKS 64              // (2048/KSPLIT)/8 ci-chunks per block

// ---- async global->LDS (gfx950), width 4 ----------------------------------
typedef __attribute__((address_space(3))) float* lds_fp;
typedef const __attribute__((address_space(1))) float* gbl_fp;
__device__ __forceinline__ void gload_lds4(const float* g, float* l) {
  __builtin_amdgcn_global_load_lds((gbl_fp)g, (lds_fp)l, 4, 0, 0);
}

// ---------------- 0. zero source for padded feature lanes ------------------
__global__ void initzero(float* z) {
  if (threadIdx.x < 16) z[threadIdx.x] = 0.f;
}

// ---------------- 1. conv 3x3, 2048 -> 1024, 50x50, pad 1 ------------------
// Lane roles (conflict-free LDS):
//   tp = tid&15 -> co (4 co each, Ws b128 @ tp*4: 64 consecutive dwords/wave)
//   g  = tid>>4 -> pos (16 pos each, Fs reads are 4-address broadcasts)
__global__ __launch_bounds__(256) void conv3x3_v6(
    const float* __restrict__ feat, const float* __restrict__ W1,
    float* __restrict__ xp, const float* __restrict__ zerop) {
  __shared__ float Ws[2][WSN];      // 2 x 18,432 B  [kk][co]
  __shared__ float Fs[2][FSN];      // 2 x 11,648 B  [ci][padded-linear window]
  const int tid = threadIdx.x;
  const int tp = tid & 15;
  const int g  = tid >> 4;
  const int q0 = blockIdx.x * POST;  // padded-linear tile base (11 tiles)
  const int co0 = blockIdx.y * 64;   // 16 co tiles
  const int bz = blockIdx.z;         // K-split 0..3 (512 ci each)

  // ---- precompute feature-staging global offsets (loop-invariant) ----
  int goffs[NSLOT];   // -1 => load from zerop (border/pad), slot s = sl*256+tid
  #pragma unroll
  for (int sl = 0; sl < NSLOT; ++sl) {
    int s = sl * 256 + tid;
    int go = -1;
    if (s < FSN) {
      int ci = s / FREG, w = s - ci * FREG;
      int pl = q0 - 53 + w;
      if (w < FWIN && pl >= 0 && pl < 2704) {
        int r = pl / 52, cc = pl - r * 52;
        if (r >= 1 && r <= 50 && cc >= 1 && cc <= 50)
          go = ci * NPOS + (r - 1) * 50 + (cc - 1);
      }
    }
    goffs[sl] = go;
  }

  // ---- weight staging pointers: co-run tp*4..tp*4+3, kk = g + 16l ----
  const float* wp0 = W1 + (size_t)(co0 + tp * 4 + 0) * 18432 + (size_t)(bz * 512) * 9 + g;
  const float* wp1 = wp0 + 18432;
  const float* wp2 = wp1 + 18432;
  const float* wp3 = wp2 + 18432;
  const int nl = (g < 8) ? 5 : 4;    // kk = g+16l < 72 (wave-uniform)
  const float* fp = feat + (size_t)(bz * 512) * NPOS;

  float acc[4][16];
  #pragma unroll
  for (int c = 0; c < 4; ++c)
    #pragma unroll
    for (int j = 0; j < 16; ++j) acc[c][j] = 0.f;

  // ---- stage chunk 0 into buffer 0 ----
  {
    float wx[5], wy[5], wz[5], ww[5];
    #pragma unroll
    for (int l = 0; l < 5; ++l)
      if (l < nl) {
        wx[l] = wp0[16 * l]; wy[l] = wp1[16 * l];
        wz[l] = wp2[16 * l]; ww[l] = wp3[16 * l];
      }
    #pragma unroll
    for (int l = 0; l < 5; ++l)
      if (l < nl) {
        float4 v = make_float4(wx[l], wy[l], wz[l], ww[l]);
        *(float4*)&Ws[0][(g + 16 * l) * 64 + tp * 4] = v;
      }
    #pragma unroll
    for (int sl = 0; sl < NSLOT; ++sl) {
      int s = sl * 256 + tid;
      if (s < FSN) {
        const float* src = (goffs[sl] >= 0) ? (fp + goffs[sl]) : zerop;
        gload_lds4(src, &Fs[0][s]);
      }
    }
  }
  __syncthreads();

  for (int ch = 0; ch < CHUNKS; ++ch) {
    const int cur = ch & 1;
    // --- stage chunk ch+1 into the other buffer (before compute; the one
    //     short weight vmcnt wait is covered by the co-resident wave) ---
    if (ch + 1 < CHUNKS) {
      wp0 += 72; wp1 += 72; wp2 += 72; wp3 += 72;
      fp += 8 * NPOS;
      float wx[5], wy[5], wz[5], ww[5];
      #pragma unroll
      for (int l = 0; l < 5; ++l)
        if (l < nl) {
          wx[l] = wp0[16 * l]; wy[l] = wp1[16 * l];
          wz[l] = wp2[16 * l]; ww[l] = wp3[16 * l];
        }
      #pragma unroll
      for (int l = 0; l < 5; ++l)
        if (l < nl) {
          float4 v = make_float4(wx[l], wy[l], wz[l], ww[l]);
          *(float4*)&Ws[1 - cur][(g + 16 * l) * 64 + tp * 4] = v;
        }
      // features: async direct-to-LDS, stays in flight through compute
      #pragma unroll
      for (int sl = 0; sl < NSLOT; ++sl) {
        int s = sl * 256 + tid;
        if (s < FSN) {
          const float* src = (goffs[sl] >= 0) ? (fp + goffs[sl]) : zerop;
          gload_lds4(src, &Fs[1 - cur][s]);
        }
      }
    }

    // --- compute chunk ch: per (ci,ky): 5 broadcast Fs reads + 3 Ws b128
    //     per 192 FMAs; 4608 FMA-instrs per thread per chunk ---
    const float* WsC = Ws[cur];
    const float* FsC = Fs[cur];
    for (int ci = 0; ci < 8; ++ci) {
      #pragma unroll
      for (int ky = 0; ky < 3; ++ky) {
        const int fb = ci * FREG + ky * 52 + g * 16;
        float4 f0 = *(const float4*)&FsC[fb];
        float4 f1 = *(const float4*)&FsC[fb + 4];
        float4 f2 = *(const float4*)&FsC[fb + 8];
        float4 f3 = *(const float4*)&FsC[fb + 12];
        float2 f4 = *(const float2*)&FsC[fb + 16];
        float f[18] = {f0.x, f0.y, f0.z, f0.w, f1.x, f1.y, f1.z, f1.w,
                       f2.x, f2.y, f2.z, f2.w, f3.x, f3.y, f3.z, f3.w,
                       f4.x, f4.y};
        #pragma unroll
        for (int kx = 0; kx < 3; ++kx) {
          float4 w = *(const float4*)&WsC[(ci * 9 + ky * 3 + kx) * 64 + tp * 4];
          #pragma unroll
          for (int j = 0; j < 16; ++j) {
            acc[0][j] += w.x * f[j + kx];
            acc[1][j] += w.y * f[j + kx];
            acc[2][j] += w.z * f[j + kx];
            acc[3][j] += w.w * f[j + kx];
          }
        }
      }
    }
    __syncthreads();   // publishes buffer 1-cur (staging drained here; loads
                       // were issued a full compute body ago -> no stall)
  }

  // --- write partial sums (plain stores) ---
  float* xpz = xp + (size_t)bz * (1024 * NPOS);
  #pragma unroll
  for (int j = 0; j < 16; ++j) {
    int pl = q0 + g * 16 + j;
    int r = pl / 52, cc = pl - r * 52;
    if (r >= 1 && r <= 50 && cc >= 1 && cc <= 50) {
      int p = (r - 1) * 50 + (cc - 1);
      #pragma unroll
      for (int c = 0; c < 4; ++c)
        xpz[(size_t)(co0 + tp * 4 + c) * NPOS + p] = acc[c][j];
    }
  }
}

// ---------------- 1b. reduce partials + bias -------------------------------
__global__ void reducex(const float* __restrict__ xp,
                        const float* __restrict__ b1, float* __restrict__ x) {
  int i = blockIdx.x * 256 + threadIdx.x;
  if (i >= 1024 * NPOS) return;
  const size_t S = (size_t)1024 * NPOS;
  float v = ((xp[i] + xp[i + S]) + (xp[i + 2 * S] + xp[i + 3 * S])) +
            b1[i / NPOS];
  x[i] = v;
}

// ---------------- 2. 1x1 conv heads (36 reg + 18 cls channels) -------------
__global__ __launch_bounds__(256) void heads(
    const float* __restrict__ x, const float* __restrict__ Wreg,
    const float* __restrict__ breg, const float* __restrict__ Wcls,
    const float* __restrict__ bcls, float* __restrict__ ho) {
  int p = blockIdx.x * 64 + threadIdx.x;
  int ch = blockIdx.y * 4 + threadIdx.y;
  if (p >= NPOS || ch >= 54) return;
  const float* w = (ch < 36) ? (Wreg + (size_t)ch * 1024)
                             : (Wcls + (size_t)(ch - 36) * 1024);
  float a0 = 0.f, a1 = 0.f, a2 = 0.f, a3 = 0.f;
  for (int c = 0; c < 1024; c += 4) {
    a0 += w[c + 0] * x[(size_t)(c + 0) * NPOS + p];
    a1 += w[c + 1] * x[(size_t)(c + 1) * NPOS + p];
    a2 += w[c + 2] * x[(size_t)(c + 2) * NPOS + p];
    a3 += w[c + 3] * x[(size_t)(c + 3) * NPOS + p];
  }
  float bias = (ch < 36) ? breg[ch] : bcls[ch - 36];
  ho[p * 56 + ch] = (a0 + a1) + (a2 + a3) + bias;
}

// ---------------- 3. decode + min-size filter + sort keys ------------------
__global__ void decodek(const float* __restrict__ ho,
                        const float* __restrict__ anchors,
                        float4* __restrict__ roi,
                        unsigned long long* __restrict__ keys) {
  int i = blockIdx.x * 256 + threadIdx.x;
  if (i >= NBOX) { keys[i] = 0ull; return; }
  int p = i / 9, a = i % 9;
  const float* hp = ho + p * 56;
  float dy = hp[a * 4 + 0], dx = hp[a * 4 + 1];
  float dh = hp[a * 4 + 2], dw = hp[a * 4 + 3];
  float s = hp[36 + a * 2 + 1];
  float ay1 = anchors[i * 4 + 0], ax1 = anchors[i * 4 + 1];
  float ay2 = anchors[i * 4 + 2], ax2 = anchors[i * 4 + 3];
  float ahh = ay2 - ay1, aww = ax2 - ax1;
  float acy = ay1 + 0.5f * ahh, acx = ax1 + 0.5f * aww;
  float cy = dy * ahh + acy, cx = dx * aww + acx;
  float h = expf(dh) * ahh, w = expf(dw) * aww;
  float y1 = fminf(fmaxf(cy - 0.5f * h, 0.f), 800.f);
  float x1 = fminf(fmaxf(cx - 0.5f * w, 0.f), 800.f);
  float y2 = fminf(fmaxf(cy + 0.5f * h, 0.f), 800.f);
  float x2 = fminf(fmaxf(cx + 0.5f * w, 0.f), 800.f);
  bool valid = ((y2 - y1) >= 16.f) && ((x2 - x1) >= 16.f);
  float sc = valid ? s : -__builtin_inff();
  unsigned u = __float_as_uint(sc);
  u = (u & 0x80000000u) ? ~u : (u | 0x80000000u);
  keys[i] = ((unsigned long long)u << 32) |
            (unsigned long long)(0xFFFFFFFFu - (unsigned)i);
  roi[i] = make_float4(y1, x1, y2, x2);
}

// ---------------- 4. bitonic sort (descending), 32768 keys -----------------
__global__ __launch_bounds__(1024) void bitonic_local(unsigned long long* keys) {
  __shared__ unsigned long long s[4096];
  int t = threadIdx.x;
  size_t base = (size_t)blockIdx.x * 4096;
  for (int m = t; m < 4096; m += 1024) s[m] = keys[base + m];
  __syncthreads();
  for (int k = 2; k <= 4096; k <<= 1) {
    for (int j = k >> 1; j > 0; j >>= 1) {
      for (int m = t; m < 4096; m += 1024) {
        int l = m ^ j;
        if (l > m) {
          bool desc = (((base + (size_t)m) & (size_t)k) == 0);
          unsigned long long a = s[m], b = s[l];
          if (desc ? (a < b) : (a > b)) { s[m] = b; s[l] = a; }
        }
      }
      __syncthreads();
    }
  }
  for (int m = t; m < 4096; m += 1024) keys[base + m] = s[m];
}

__global__ __launch_bounds__(1024) void bitonic_merge_local(
    unsigned long long* keys, int k) {
  __shared__ unsigned long long s[4096];
  int t = threadIdx.x;
  size_t base = (size_t)blockIdx.x * 4096;
  for (int m = t; m < 4096; m += 1024) s[m] = keys[base + m];
  __syncthreads();
  for (int j = 2048; j > 0; j >>= 1) {
    for (int m = t; m < 4096; m += 1024) {
      int l = m ^ j;
      if (l > m) {
        bool desc = (((base + (size_t)m) & (size_t)k) == 0);
        unsigned long long a = s[m], b = s[l];
        if (desc ? (a < b) : (a > b)) { s[m] = b; s[l] = a; }
      }
    }
    __syncthreads();
  }
  for (int m = t; m < 4096; m += 1024) keys[base + m] = s[m];
}

__global__ void bitonic_global(unsigned long long* keys, int k, int j) {
  int m = blockIdx.x * 256 + threadIdx.x;
  int l = m ^ j;
  if (l > m) {
    bool desc = ((m & k) == 0);
    unsigned long long a = keys[m], b = keys[l];
    if (desc ? (a < b) : (a > b)) { keys[m] = b; keys[l] = a; }
  }
}

// ---------------- 5. gather sorted top-6000 boxes + valid flags ------------
__global__ void gatherk(const unsigned long long* __restrict__ keys,
                        const float4* __restrict__ roi,
                        float4* __restrict__ sbox, int* __restrict__ validArr) {
  int t = blockIdx.x * 256 + threadIdx.x;
  if (t >= NPRE) return;
  unsigned long long k = keys[t];
  unsigned u = (unsigned)(k >> 32);
  int valid = (u > 0x007FFFFFu) ? 1 : 0;
  float4 b = make_float4(0.f, 0.f, 0.f, 0.f);
  if (valid) {
    int idx = (int)(0xFFFFFFFFu - (unsigned)(k & 0xFFFFFFFFull));
    b = roi[idx];
  }
  sbox[t] = b;
  validArr[t] = valid;
}

// ---------------- 6. NMS suppression bitmask -------------------------------
__global__ __launch_bounds__(64) void nmsmask(
    const float4* __restrict__ sbox, unsigned long long* __restrict__ mask) {
  int rb = blockIdx.x, cb = blockIdx.y;
  int t = threadIdx.x;
  __shared__ float4 cbx[64];
  __shared__ float car[64];
  int jj = cb * 64 + t;
  float4 c = (jj < NPRE) ? sbox[jj] : make_float4(0.f, 0.f, 0.f, 0.f);
  cbx[t] = c;
  car[t] = (c.w - c.y + 1.f) * (c.z - c.x + 1.f);
  __syncthreads();
  int i = rb * 64 + t;
  if (i >= NPRE) return;
  float4 b = sbox[i];
  float ai = (b.w - b.y + 1.f) * (b.z - b.x + 1.f);
  unsigned long long bits = 0ull;
  int nj = min(64, NPRE - cb * 64);
  for (int j = 0; j < nj; ++j) {
    float4 cc = cbx[j];
    float yy1 = fmaxf(b.x, cc.x), xx1 = fmaxf(b.y, cc.y);
    float yy2 = fminf(b.z, cc.z), xx2 = fminf(b.w, cc.w);
    float inter = fmaxf(xx2 - xx1 + 1.f, 0.f) * fmaxf(yy2 - yy1 + 1.f, 0.f);
    float iou = inter / (ai + car[j] - inter);
    if (iou > 0.7f) bits |= (1ull << j);
  }
  mask[(size_t)i * NWORDS + cb] = bits;
}

// ---------------- 7. greedy scan (single wave) + output --------------------
__global__ __launch_bounds__(64) void nmsscan(
    const unsigned long long* __restrict__ mask,
    const int* __restrict__ validArr, const float4* __restrict__ sbox,
    float* __restrict__ out) {
  int t = threadIdx.x;
  __shared__ unsigned long long remv[NWORDS];
  __shared__ int keepIdx[NPOST];
  remv[t] = 0ull;
  if (t + 64 < NWORDS) remv[t + 64] = 0ull;
  __syncthreads();
  int nk = 0;
  for (int wb = 0; wb < NWORDS && nk < NPOST; ++wb) {
    int gi = wb * 64 + t;
    bool v = (gi < NPRE) && (validArr[gi] != 0);
    unsigned long long avail = __ballot(v);
    avail &= ~remv[wb];
    while (avail != 0ull && nk < NPOST) {
      int b = __ffsll((unsigned long long)avail) - 1;
      int i = wb * 64 + b;
      if (t == 0) keepIdx[nk] = i;
      nk++;
      const unsigned long long* row = mask + (size_t)i * NWORDS;
      remv[t] |= row[t];
      if (t + 64 < NWORDS) remv[t + 64] |= row[t + 64];
      __syncthreads();
      avail &= ~remv[wb];
    }
  }
  __syncthreads();
  for (int r = t; r < NPOST; r += 64) {
    float4 bx = make_float4(0.f, 0.f, 0.f, 0.f);
    if (r < nk) bx = sbox[keepIdx[r]];
    reinterpret_cast<float4*>(out)[r] = bx;
  }
}

// ---------------------------------------------------------------------------
extern "C" void kernel_launch(void* const* d_in, const int* in_sizes, int n_in,
                              void* d_out, int out_size, void* d_ws,
                              size_t ws_size, hipStream_t stream) {
  const float* feat    = (const float*)d_in[0];
  const float* anchors = (const float*)d_in[1];
  const float* W1      = (const float*)d_in[2];
  const float* b1      = (const float*)d_in[3];
  const float* Wreg    = (const float*)d_in[4];
  const float* breg    = (const float*)d_in[5];
  const float* Wcls    = (const float*)d_in[6];
  const float* bcls    = (const float*)d_in[7];

  char* ws = (char*)d_ws;
  float* x                 = (float*)(ws);             // 10,240,000 B
  float* xp                = (float*)(ws + 10240000);  // 40,960,000 B (dead after reducex)
  // aliases inside xp (written strictly after reducex):
  float4* sbox             = (float4*)(ws + 10240000);          //     96,256 B
  int* validArr            = (int*)(ws + 10336256);             //     24,064 B
  unsigned long long* mask = (unsigned long long*)(ws + 10360320); // 4,524,032 B
  float* ho                = (float*)(ws + 51200000);  //    560,000 B
  float4* roi              = (float4*)(ws + 51760000); //    360,000 B
  unsigned long long* keys = (unsigned long long*)(ws + 52120000); // 262,144 B
  // zero source for conv feature padding: aliases keys[0..15] (keys is dead
  // during conv; decodek rewrites it afterwards, same order every launch)
  float* zerop             = (float*)(ws + 52120000);
  float* out = (float*)d_out;

  initzero<<<1, 64, 0, stream>>>(zerop);
  conv3x3_v6<<<dim3(11, 16, KSPLIT), 256, 0, stream>>>(feat, W1, xp, zerop);
  reducex<<<10000, 256, 0, stream>>>(xp, b1, x);
  heads<<<dim3(40, 14), dim3(64, 4), 0, stream>>>(x, Wreg, breg, Wcls, bcls, ho);
  decodek<<<128, 256, 0, stream>>>(ho, anchors, roi, keys);

  bitonic_local<<<8, 1024, 0, stream>>>(keys);
  for (int k = 8192; k <= NSORT; k <<= 1) {
    for (int j = k >> 1; j >= 4096; j >>= 1)
      bitonic_global<<<128, 256, 0, stream>>>(keys, k, j);
    bitonic_merge_local<<<8, 1024, 0, stream>>>(keys, k);
  }

  gatherk<<<24, 256, 0, stream>>>(keys, roi, sbox, validArr);
  nmsmask<<<dim3(NWORDS, NWORDS), 64, 0, stream>>>(sbox, mask);
  nmsscan<<<1, 64, 0, stream>>>(mask, validArr, sbox, out);
}

// Round 7
// 2173.572 us; speedup vs baseline: 1.3071x; 1.0234x over previous
//
#include <hip/hip_runtime.h>
#include <hip/hip_bf16.h>

// ---------------------------------------------------------------------------
// RPN pipeline:
//  0. initzero  : zero the gl_lds zero-source dwords (aliases keys region)
//  1. conv3x3_v7: fp32 reg-tiled conv 2048->1024, K-split x4, partial sums.
//                 4-ci double-buffered chunks sized for 4 waves/SIMD:
//                 LDS 28KB (5 blocks/CU), acc 4x12, launch_bounds(256,4)
//                 caps VGPR at 128 (v6 was 132 -> 2 waves/SIMD cliff).
//                 Features staged async via global_load_lds; weights via
//                 short-lived register round-trip.
//  1b. reducex  : x = xp0+xp1+xp2+xp3 + bias (deterministic)
//  2. heads     : 1x1 convs (36 reg + 18 cls channels)  -> ho[2500][56]
//  3. decode    : box decode + clip + min-size filter   -> roi, sort keys
//  4. bitonic   : descending stable sort of 32768 64-bit keys
//  5. gather    : sorted boxes + valid flags
//  6. nmsmask   : 6000x6000 IoU suppression bitmask
//  7. nmsscan   : single-wave greedy scan (<=300 keeps) + write output
// ---------------------------------------------------------------------------

#define NPOS 2500
#define NBOX 22500
#define NSORT 32768
#define NPRE 6000
#define NWORDS 94
#define NPOST 300

// conv tiling (v7)
#define POST 192               // positions per block (padded-linear)
#define PPT 12                 // positions per thread (16B-aligned LDS reads)
#define FWIN 298               // POST + 106 halo
#define FREG 300               // padded row stride (dwords), multiple of 4
#define CICH 4                 // ci per chunk
#define WROWS 36               // CICH * 9 taps
#define FSN  (CICH * FREG)     // 1200 dwords per feature buffer
#define WSN  (WROWS * 64)      // 2304 dwords per weight buffer
#define NSLOT 5                // ceil(FSN/256)
#define KSPLIT 4
#define CHUNKS 128             // (2048/KSPLIT)/CICH chunks per block
#define NPT 15                 // ceil(2704/POST) position tiles

// ---- async global->LDS (gfx950), width 4 ----------------------------------
typedef __attribute__((address_space(3))) float* lds_fp;
typedef const __attribute__((address_space(1))) float* gbl_fp;
__device__ __forceinline__ void gload_lds4(const float* g, float* l) {
  __builtin_amdgcn_global_load_lds((gbl_fp)g, (lds_fp)l, 4, 0, 0);
}

// ---------------- 0. zero source for padded feature lanes ------------------
__global__ void initzero(float* z) {
  if (threadIdx.x < 16) z[threadIdx.x] = 0.f;
}

// ---------------- 1. conv 3x3, 2048 -> 1024, 50x50, pad 1 ------------------
// Lane roles (conflict-free LDS):
//   tp = tid&15 -> co (4 co each, Ws b128 @ tp*4: 64 consecutive dwords/wave)
//   g  = tid>>4 -> pos (12 pos each, Fs reads are 4-address broadcasts)
__global__ __launch_bounds__(256, 4) void conv3x3_v7(
    const float* __restrict__ feat, const float* __restrict__ W1,
    float* __restrict__ xp, const float* __restrict__ zerop) {
  __shared__ float Ws[2][WSN];      // 2 x  9,216 B  [kk][co]
  __shared__ float Fs[2][FSN];      // 2 x  4,800 B  [ci][padded-linear window]
  const int tid = threadIdx.x;
  const int tp = tid & 15;
  const int g  = tid >> 4;
  const int q0 = blockIdx.x * POST;  // padded-linear tile base (15 tiles)
  const int co0 = blockIdx.y * 64;   // 16 co tiles
  const int bz = blockIdx.z;         // K-split 0..3 (512 ci each)

  // ---- precompute feature-staging global offsets (loop-invariant) ----
  int goffs[NSLOT];   // -1 => load from zerop (border/pad), slot s = sl*256+tid
  #pragma unroll
  for (int sl = 0; sl < NSLOT; ++sl) {
    int s = sl * 256 + tid;
    int go = -1;
    if (s < FSN) {
      int ci = s / FREG, w = s - ci * FREG;
      int pl = q0 - 53 + w;
      if (w < FWIN && pl >= 0 && pl < 2704) {
        int r = pl / 52, cc = pl - r * 52;
        if (r >= 1 && r <= 50 && cc >= 1 && cc <= 50)
          go = ci * NPOS + (r - 1) * 50 + (cc - 1);
      }
    }
    goffs[sl] = go;
  }

  // ---- weight staging pointers: co-run tp*4..tp*4+3, kk = g + 16l ----
  const float* wp0 = W1 + (size_t)(co0 + tp * 4 + 0) * 18432 + (size_t)(bz * 512) * 9 + g;
  const float* wp1 = wp0 + 18432;
  const float* wp2 = wp1 + 18432;
  const float* wp3 = wp2 + 18432;
  const int nl = (g < 4) ? 3 : 2;    // kk = g+16l < 36 (wave-uniform-ish)
  const float* fp = feat + (size_t)(bz * 512) * NPOS;

  float acc[4][PPT];
  #pragma unroll
  for (int c = 0; c < 4; ++c)
    #pragma unroll
    for (int j = 0; j < PPT; ++j) acc[c][j] = 0.f;

  // ---- stage chunk 0 into buffer 0 ----
  {
    float wx[3], wy[3], wz[3], ww[3];
    #pragma unroll
    for (int l = 0; l < 3; ++l)
      if (l < nl) {
        wx[l] = wp0[16 * l]; wy[l] = wp1[16 * l];
        wz[l] = wp2[16 * l]; ww[l] = wp3[16 * l];
      }
    #pragma unroll
    for (int sl = 0; sl < NSLOT; ++sl) {
      int s = sl * 256 + tid;
      if (s < FSN) {
        const float* src = (goffs[sl] >= 0) ? (fp + goffs[sl]) : zerop;
        gload_lds4(src, &Fs[0][s]);
      }
    }
    #pragma unroll
    for (int l = 0; l < 3; ++l)
      if (l < nl) {
        float4 v = make_float4(wx[l], wy[l], wz[l], ww[l]);
        *(float4*)&Ws[0][(g + 16 * l) * 64 + tp * 4] = v;
      }
  }
  __syncthreads();

  for (int ch = 0; ch < CHUNKS; ++ch) {
    const int cur = ch & 1;
    // --- stage chunk ch+1 into the other buffer ---
    if (ch + 1 < CHUNKS) {
      wp0 += WROWS; wp1 += WROWS; wp2 += WROWS; wp3 += WROWS;
      fp += CICH * NPOS;
      float wx[3], wy[3], wz[3], ww[3];
      #pragma unroll
      for (int l = 0; l < 3; ++l)
        if (l < nl) {
          wx[l] = wp0[16 * l]; wy[l] = wp1[16 * l];
          wz[l] = wp2[16 * l]; ww[l] = wp3[16 * l];
        }
      // features: async direct-to-LDS, in flight through the compute body
      #pragma unroll
      for (int sl = 0; sl < NSLOT; ++sl) {
        int s = sl * 256 + tid;
        if (s < FSN) {
          const float* src = (goffs[sl] >= 0) ? (fp + goffs[sl]) : zerop;
          gload_lds4(src, &Fs[1 - cur][s]);
        }
      }
      #pragma unroll
      for (int l = 0; l < 3; ++l)
        if (l < nl) {
          float4 v = make_float4(wx[l], wy[l], wz[l], ww[l]);
          *(float4*)&Ws[1 - cur][(g + 16 * l) * 64 + tp * 4] = v;
        }
    }

    // --- compute chunk ch: per (ci,ky): 4 broadcast Fs b128 + 3 Ws b128
    //     per 144 FMAs; 1728 FMA-instrs per thread per chunk ---
    const float* WsC = Ws[cur];
    const float* FsC = Fs[cur];
    #pragma unroll
    for (int ci = 0; ci < CICH; ++ci) {
      #pragma unroll
      for (int ky = 0; ky < 3; ++ky) {
        const int fb = ci * FREG + ky * 52 + g * PPT;  // all terms %4==0
        float4 f0 = *(const float4*)&FsC[fb];
        float4 f1 = *(const float4*)&FsC[fb + 4];
        float4 f2 = *(const float4*)&FsC[fb + 8];
        float4 f3 = *(const float4*)&FsC[fb + 12];
        float f[16] = {f0.x, f0.y, f0.z, f0.w, f1.x, f1.y, f1.z, f1.w,
                       f2.x, f2.y, f2.z, f2.w, f3.x, f3.y, f3.z, f3.w};
        #pragma unroll
        for (int kx = 0; kx < 3; ++kx) {
          float4 w = *(const float4*)&WsC[(ci * 9 + ky * 3 + kx) * 64 + tp * 4];
          #pragma unroll
          for (int j = 0; j < PPT; ++j) {
            acc[0][j] += w.x * f[j + kx];
            acc[1][j] += w.y * f[j + kx];
            acc[2][j] += w.z * f[j + kx];
            acc[3][j] += w.w * f[j + kx];
          }
        }
      }
    }
    __syncthreads();   // staging loads were issued a full compute body ago
  }

  // --- write partial sums (plain stores) ---
  float* xpz = xp + (size_t)bz * (1024 * NPOS);
  #pragma unroll
  for (int j = 0; j < PPT; ++j) {
    int pl = q0 + g * PPT + j;
    int r = pl / 52, cc = pl - r * 52;
    if (pl < 2704 && r >= 1 && r <= 50 && cc >= 1 && cc <= 50) {
      int p = (r - 1) * 50 + (cc - 1);
      #pragma unroll
      for (int c = 0; c < 4; ++c)
        xpz[(size_t)(co0 + tp * 4 + c) * NPOS + p] = acc[c][j];
    }
  }
}

// ---------------- 1b. reduce partials + bias -------------------------------
__global__ void reducex(const float* __restrict__ xp,
                        const float* __restrict__ b1, float* __restrict__ x) {
  int i = blockIdx.x * 256 + threadIdx.x;
  if (i >= 1024 * NPOS) return;
  const size_t S = (size_t)1024 * NPOS;
  float v = ((xp[i] + xp[i + S]) + (xp[i + 2 * S] + xp[i + 3 * S])) +
            b1[i / NPOS];
  x[i] = v;
}

// ---------------- 2. 1x1 conv heads (36 reg + 18 cls channels) -------------
__global__ __launch_bounds__(256) void heads(
    const float* __restrict__ x, const float* __restrict__ Wreg,
    const float* __restrict__ breg, const float* __restrict__ Wcls,
    const float* __restrict__ bcls, float* __restrict__ ho) {
  int p = blockIdx.x * 64 + threadIdx.x;
  int ch = blockIdx.y * 4 + threadIdx.y;
  if (p >= NPOS || ch >= 54) return;
  const float* w = (ch < 36) ? (Wreg + (size_t)ch * 1024)
                             : (Wcls + (size_t)(ch - 36) * 1024);
  float a0 = 0.f, a1 = 0.f, a2 = 0.f, a3 = 0.f;
  for (int c = 0; c < 1024; c += 4) {
    a0 += w[c + 0] * x[(size_t)(c + 0) * NPOS + p];
    a1 += w[c + 1] * x[(size_t)(c + 1) * NPOS + p];
    a2 += w[c + 2] * x[(size_t)(c + 2) * NPOS + p];
    a3 += w[c + 3] * x[(size_t)(c + 3) * NPOS + p];
  }
  float bias = (ch < 36) ? breg[ch] : bcls[ch - 36];
  ho[p * 56 + ch] = (a0 + a1) + (a2 + a3) + bias;
}

// ---------------- 3. decode + min-size filter + sort keys ------------------
__global__ void decodek(const float* __restrict__ ho,
                        const float* __restrict__ anchors,
                        float4* __restrict__ roi,
                        unsigned long long* __restrict__ keys) {
  int i = blockIdx.x * 256 + threadIdx.x;
  if (i >= NBOX) { keys[i] = 0ull; return; }
  int p = i / 9, a = i % 9;
  const float* hp = ho + p * 56;
  float dy = hp[a * 4 + 0], dx = hp[a * 4 + 1];
  float dh = hp[a * 4 + 2], dw = hp[a * 4 + 3];
  float s = hp[36 + a * 2 + 1];
  float ay1 = anchors[i * 4 + 0], ax1 = anchors[i * 4 + 1];
  float ay2 = anchors[i * 4 + 2], ax2 = anchors[i * 4 + 3];
  float ahh = ay2 - ay1, aww = ax2 - ax1;
  float acy = ay1 + 0.5f * ahh, acx = ax1 + 0.5f * aww;
  float cy = dy * ahh + acy, cx = dx * aww + acx;
  float h = expf(dh) * ahh, w = expf(dw) * aww;
  float y1 = fminf(fmaxf(cy - 0.5f * h, 0.f), 800.f);
  float x1 = fminf(fmaxf(cx - 0.5f * w, 0.f), 800.f);
  float y2 = fminf(fmaxf(cy + 0.5f * h, 0.f), 800.f);
  float x2 = fminf(fmaxf(cx + 0.5f * w, 0.f), 800.f);
  bool valid = ((y2 - y1) >= 16.f) && ((x2 - x1) >= 16.f);
  float sc = valid ? s : -__builtin_inff();
  unsigned u = __float_as_uint(sc);
  u = (u & 0x80000000u) ? ~u : (u | 0x80000000u);
  keys[i] = ((unsigned long long)u << 32) |
            (unsigned long long)(0xFFFFFFFFu - (unsigned)i);
  roi[i] = make_float4(y1, x1, y2, x2);
}

// ---------------- 4. bitonic sort (descending), 32768 keys -----------------
__global__ __launch_bounds__(1024) void bitonic_local(unsigned long long* keys) {
  __shared__ unsigned long long s[4096];
  int t = threadIdx.x;
  size_t base = (size_t)blockIdx.x * 4096;
  for (int m = t; m < 4096; m += 1024) s[m] = keys[base + m];
  __syncthreads();
  for (int k = 2; k <= 4096; k <<= 1) {
    for (int j = k >> 1; j > 0; j >>= 1) {
      for (int m = t; m < 4096; m += 1024) {
        int l = m ^ j;
        if (l > m) {
          bool desc = (((base + (size_t)m) & (size_t)k) == 0);
          unsigned long long a = s[m], b = s[l];
          if (desc ? (a < b) : (a > b)) { s[m] = b; s[l] = a; }
        }
      }
      __syncthreads();
    }
  }
  for (int m = t; m < 4096; m += 1024) keys[base + m] = s[m];
}

__global__ __launch_bounds__(1024) void bitonic_merge_local(
    unsigned long long* keys, int k) {
  __shared__ unsigned long long s[4096];
  int t = threadIdx.x;
  size_t base = (size_t)blockIdx.x * 4096;
  for (int m = t; m < 4096; m += 1024) s[m] = keys[base + m];
  __syncthreads();
  for (int j = 2048; j > 0; j >>= 1) {
    for (int m = t; m < 4096; m += 1024) {
      int l = m ^ j;
      if (l > m) {
        bool desc = (((base + (size_t)m) & (size_t)k) == 0);
        unsigned long long a = s[m], b = s[l];
        if (desc ? (a < b) : (a > b)) { s[m] = b; s[l] = a; }
      }
    }
    __syncthreads();
  }
  for (int m = t; m < 4096; m += 1024) keys[base + m] = s[m];
}

__global__ void bitonic_global(unsigned long long* keys, int k, int j) {
  int m = blockIdx.x * 256 + threadIdx.x;
  int l = m ^ j;
  if (l > m) {
    bool desc = ((m & k) == 0);
    unsigned long long a = keys[m], b = keys[l];
    if (desc ? (a < b) : (a > b)) { keys[m] = b; keys[l] = a; }
  }
}

// ---------------- 5. gather sorted top-6000 boxes + valid flags ------------
__global__ void gatherk(const unsigned long long* __restrict__ keys,
                        const float4* __restrict__ roi,
                        float4* __restrict__ sbox, int* __restrict__ validArr) {
  int t = blockIdx.x * 256 + threadIdx.x;
  if (t >= NPRE) return;
  unsigned long long k = keys[t];
  unsigned u = (unsigned)(k >> 32);
  int valid = (u > 0x007FFFFFu) ? 1 : 0;
  float4 b = make_float4(0.f, 0.f, 0.f, 0.f);
  if (valid) {
    int idx = (int)(0xFFFFFFFFu - (unsigned)(k & 0xFFFFFFFFull));
    b = roi[idx];
  }
  sbox[t] = b;
  validArr[t] = valid;
}

// ---------------- 6. NMS suppression bitmask -------------------------------
__global__ __launch_bounds__(64) void nmsmask(
    const float4* __restrict__ sbox, unsigned long long* __restrict__ mask) {
  int rb = blockIdx.x, cb = blockIdx.y;
  int t = threadIdx.x;
  __shared__ float4 cbx[64];
  __shared__ float car[64];
  int jj = cb * 64 + t;
  float4 c = (jj < NPRE) ? sbox[jj] : make_float4(0.f, 0.f, 0.f, 0.f);
  cbx[t] = c;
  car[t] = (c.w - c.y + 1.f) * (c.z - c.x + 1.f);
  __syncthreads();
  int i = rb * 64 + t;
  if (i >= NPRE) return;
  float4 b = sbox[i];
  float ai = (b.w - b.y + 1.f) * (b.z - b.x + 1.f);
  unsigned long long bits = 0ull;
  int nj = min(64, NPRE - cb * 64);
  for (int j = 0; j < nj; ++j) {
    float4 cc = cbx[j];
    float yy1 = fmaxf(b.x, cc.x), xx1 = fmaxf(b.y, cc.y);
    float yy2 = fminf(b.z, cc.z), xx2 = fminf(b.w, cc.w);
    float inter = fmaxf(xx2 - xx1 + 1.f, 0.f) * fmaxf(yy2 - yy1 + 1.f, 0.f);
    float iou = inter / (ai + car[j] - inter);
    if (iou > 0.7f) bits |= (1ull << j);
  }
  mask[(size_t)i * NWORDS + cb] = bits;
}

// ---------------- 7. greedy scan (single wave) + output --------------------
__global__ __launch_bounds__(64) void nmsscan(
    const unsigned long long* __restrict__ mask,
    const int* __restrict__ validArr, const float4* __restrict__ sbox,
    float* __restrict__ out) {
  int t = threadIdx.x;
  __shared__ unsigned long long remv[NWORDS];
  __shared__ int keepIdx[NPOST];
  remv[t] = 0ull;
  if (t + 64 < NWORDS) remv[t + 64] = 0ull;
  __syncthreads();
  int nk = 0;
  for (int wb = 0; wb < NWORDS && nk < NPOST; ++wb) {
    int gi = wb * 64 + t;
    bool v = (gi < NPRE) && (validArr[gi] != 0);
    unsigned long long avail = __ballot(v);
    avail &= ~remv[wb];
    while (avail != 0ull && nk < NPOST) {
      int b = __ffsll((unsigned long long)avail) - 1;
      int i = wb * 64 + b;
      if (t == 0) keepIdx[nk] = i;
      nk++;
      const unsigned long long* row = mask + (size_t)i * NWORDS;
      remv[t] |= row[t];
      if (t + 64 < NWORDS) remv[t + 64] |= row[t + 64];
      __syncthreads();
      avail &= ~remv[wb];
    }
  }
  __syncthreads();
  for (int r = t; r < NPOST; r += 64) {
    float4 bx = make_float4(0.f, 0.f, 0.f, 0.f);
    if (r < nk) bx = sbox[keepIdx[r]];
    reinterpret_cast<float4*>(out)[r] = bx;
  }
}

// ---------------------------------------------------------------------------
extern "C" void kernel_launch(void* const* d_in, const int* in_sizes, int n_in,
                              void* d_out, int out_size, void* d_ws,
                              size_t ws_size, hipStream_t stream) {
  const float* feat    = (const float*)d_in[0];
  const float* anchors = (const float*)d_in[1];
  const float* W1      = (const float*)d_in[2];
  const float* b1      = (const float*)d_in[3];
  const float* Wreg    = (const float*)d_in[4];
  const float* breg    = (const float*)d_in[5];
  const float* Wcls    = (const float*)d_in[6];
  const float* bcls    = (const float*)d_in[7];

  char* ws = (char*)d_ws;
  float* x                 = (float*)(ws);             // 10,240,000 B
  float* xp                = (float*)(ws + 10240000);  // 40,960,000 B (dead after reducex)
  // aliases inside xp (written strictly after reducex):
  float4* sbox             = (float4*)(ws + 10240000);          //     96,256 B
  int* validArr            = (int*)(ws + 10336256);             //     24,064 B
  unsigned long long* mask = (unsigned long long*)(ws + 10360320); // 4,524,032 B
  float* ho                = (float*)(ws + 51200000);  //    560,000 B
  float4* roi              = (float4*)(ws + 51760000); //    360,000 B
  unsigned long long* keys = (unsigned long long*)(ws + 52120000); // 262,144 B
  // zero source for conv feature padding: aliases keys[0..15] (keys is dead
  // during conv; decodek rewrites it afterwards, same order every launch)
  float* zerop             = (float*)(ws + 52120000);
  float* out = (float*)d_out;

  initzero<<<1, 64, 0, stream>>>(zerop);
  conv3x3_v7<<<dim3(NPT, 16, KSPLIT), 256, 0, stream>>>(feat, W1, xp, zerop);
  reducex<<<10000, 256, 0, stream>>>(xp, b1, x);
  heads<<<dim3(40, 14), dim3(64, 4), 0, stream>>>(x, Wreg, breg, Wcls, bcls, ho);
  decodek<<<128, 256, 0, stream>>>(ho, anchors, roi, keys);

  bitonic_local<<<8, 1024, 0, stream>>>(keys);
  for (int k = 8192; k <= NSORT; k <<= 1) {
    for (int j = k >> 1; j >= 4096; j >>= 1)
      bitonic_global<<<128, 256, 0, stream>>>(keys, k, j);
    bitonic_merge_local<<<8, 1024, 0, stream>>>(keys, k);
  }

  gatherk<<<24, 256, 0, stream>>>(keys, roi, sbox, validArr);
  nmsmask<<<dim3(NWORDS, NWORDS), 64, 0, stream>>>(sbox, mask);
  nmsscan<<<1, 64, 0, stream>>>(mask, validArr, sbox, out);
}

// Round 8
// 1897.626 us; speedup vs baseline: 1.4971x; 1.1454x over previous
//
#include <hip/hip_runtime.h>
#include <hip/hip_bf16.h>

// ---------------------------------------------------------------------------
// RPN pipeline:
//  0a. initzero  : zero the gl_lds zero-source dwords (aliases keys region)
//  0b. transposeW: W1[co][ci*9+t] -> Wt[ci*9+t][co]  (64x64 LDS tile transpose)
//  1. conv3x3_v8 : fp32 reg-tiled conv 2048->1024, K-split x4, partial sums.
//                  FULLY-ASYNC staging: BOTH weights (from Wt) and features
//                  go global->LDS via global_load_lds, double-buffered, one
//                  barrier per chunk. No vmcnt waits in the K-loop body; the
//                  barrier drain targets loads issued a full compute body
//                  (~3500 cyc) earlier. (v7's weight reg round-trip exposed a
//                  per-chunk vmcnt stall = ~60% of conv time.)
//  1b. reducex   : x = xp0+xp1+xp2+xp3 + bias (deterministic)
//  2. heads      : 1x1 convs (36 reg + 18 cls channels)  -> ho[2500][56]
//  3. decode     : box decode + clip + min-size filter   -> roi, sort keys
//  4. bitonic    : descending stable sort of 32768 64-bit keys
//  5. gather     : sorted boxes + valid flags
//  6. nmsmask    : 6000x6000 IoU suppression bitmask
//  7. nmsscan    : single-wave greedy scan (<=300 keeps) + write output
// ---------------------------------------------------------------------------

#define NPOS 2500
#define NBOX 22500
#define NSORT 32768
#define NPRE 6000
#define NWORDS 94
#define NPOST 300

// conv tiling (v8)
#define POST 192               // positions per block (padded-linear)
#define PPT 12                 // positions per thread (16B-aligned LDS reads)
#define FWIN 298               // POST + 106 halo
#define FREG 300               // padded row stride (dwords), multiple of 4
#define CICH 4                 // ci per chunk
#define WROWS 36               // CICH * 9 taps
#define FSN  (CICH * FREG)     // 1200 dwords per feature buffer
#define WSN  (WROWS * 64)      // 2304 dwords per weight buffer
#define NSLOT 5                // ceil(FSN/256)
#define WSLOT 9                // WSN/256
#define KSPLIT 4
#define CHUNKS 128             // (2048/KSPLIT)/CICH chunks per block
#define NPT 15                 // ceil(2704/POST) position tiles

// ---- async global->LDS (gfx950), width 4 ----------------------------------
typedef __attribute__((address_space(3))) float* lds_fp;
typedef const __attribute__((address_space(1))) float* gbl_fp;
__device__ __forceinline__ void gload_lds4(const float* g, float* l) {
  __builtin_amdgcn_global_load_lds((gbl_fp)g, (lds_fp)l, 4, 0, 0);
}

// ---------------- 0a. zero source for padded feature lanes -----------------
__global__ void initzero(float* z) {
  if (threadIdx.x < 16) z[threadIdx.x] = 0.f;
}

// ---------------- 0b. weight transpose: W1[co][R] -> Wt[R][co] -------------
// R = ci*9 + tap, 18432 rows x 1024 cols. 64x64 tiles via padded LDS.
__global__ __launch_bounds__(256) void transposeW(
    const float* __restrict__ W1, float* __restrict__ Wt) {
  __shared__ float T[64][65];
  const int R0 = blockIdx.x * 64;   // 288 tiles
  const int c0 = blockIdx.y * 64;   // 16 tiles
  const int a = threadIdx.x & 63;
  const int b = threadIdx.x >> 6;   // 0..3
  #pragma unroll
  for (int k = 0; k < 16; ++k) {
    int co = b + k * 4;
    T[co][a] = W1[(size_t)(c0 + co) * 18432 + R0 + a];  // coalesced in a
  }
  __syncthreads();
  #pragma unroll
  for (int k = 0; k < 16; ++k) {
    int r = b + k * 4;
    Wt[(size_t)(R0 + r) * 1024 + c0 + a] = T[a][r];     // coalesced in a
  }
}

// ---------------- 1. conv 3x3, 2048 -> 1024, 50x50, pad 1 ------------------
// Lane roles (conflict-free LDS):
//   tp = tid&15 -> co (4 co each, Ws b128 @ tp*4: 64 consecutive dwords/wave)
//   g  = tid>>4 -> pos (12 pos each, Fs reads are 4-address broadcasts)
__global__ __launch_bounds__(256, 4) void conv3x3_v8(
    const float* __restrict__ feat, const float* __restrict__ Wt,
    float* __restrict__ xp, const float* __restrict__ zerop) {
  __shared__ float Ws[2][WSN];      // 2 x  9,216 B  [kk][co]
  __shared__ float Fs[2][FSN];      // 2 x  4,800 B  [ci][padded-linear window]
  const int tid = threadIdx.x;
  const int tp = tid & 15;
  const int g  = tid >> 4;
  const int q0 = blockIdx.x * POST;  // padded-linear tile base (15 tiles)
  const int co0 = blockIdx.y * 64;   // 16 co tiles
  const int bz = blockIdx.z;         // K-split 0..3 (512 ci each)

  // ---- precompute feature-staging global offsets (loop-invariant) ----
  int goffs[NSLOT];   // -1 => load from zerop (border/pad), slot s = sl*256+tid
  #pragma unroll
  for (int sl = 0; sl < NSLOT; ++sl) {
    int s = sl * 256 + tid;
    int go = -1;
    if (s < FSN) {
      int ci = s / FREG, w = s - ci * FREG;
      int pl = q0 - 53 + w;
      if (w < FWIN && pl >= 0 && pl < 2704) {
        int r = pl / 52, cc = pl - r * 52;
        if (r >= 1 && r <= 50 && cc >= 1 && cc <= 50)
          go = ci * NPOS + (r - 1) * 50 + (cc - 1);
      }
    }
    goffs[sl] = go;
  }

  // ---- weight staging pointer: slot s = sl*256+tid covers Ws row s>>6,
  //      col s&63; global src = Wt[(bz*4608 + ch*36 + (s>>6))*1024 + co0 +
  //      (s&63)]. Per-wave: one full 64-dword row -> coalesced 256B. ----
  const float* pb = Wt + ((size_t)(bz * 4608) + (tid >> 6)) * 1024 + co0 +
                    (tid & 63);
  const float* fp = feat + (size_t)(bz * 512) * NPOS;

  float acc[4][PPT];
  #pragma unroll
  for (int c = 0; c < 4; ++c)
    #pragma unroll
    for (int j = 0; j < PPT; ++j) acc[c][j] = 0.f;

  // ---- stage chunk 0 into buffer 0 (all async) ----
  #pragma unroll
  for (int sl = 0; sl < WSLOT; ++sl)
    gload_lds4(pb + sl * 4096, &Ws[0][sl * 256 + tid]);
  #pragma unroll
  for (int sl = 0; sl < NSLOT; ++sl) {
    int s = sl * 256 + tid;
    if (s < FSN) {
      const float* src = (goffs[sl] >= 0) ? (fp + goffs[sl]) : zerop;
      gload_lds4(src, &Fs[0][s]);
    }
  }
  __syncthreads();

  for (int ch = 0; ch < CHUNKS; ++ch) {
    const int cur = ch & 1;
    // --- stage chunk ch+1 into the other buffer (async, no waits; drains
    //     at the barrier below, a full compute body after issue) ---
    if (ch + 1 < CHUNKS) {
      pb += WROWS * 1024;
      fp += CICH * NPOS;
      #pragma unroll
      for (int sl = 0; sl < WSLOT; ++sl)
        gload_lds4(pb + sl * 4096, &Ws[1 - cur][sl * 256 + tid]);
      #pragma unroll
      for (int sl = 0; sl < NSLOT; ++sl) {
        int s = sl * 256 + tid;
        if (s < FSN) {
          const float* src = (goffs[sl] >= 0) ? (fp + goffs[sl]) : zerop;
          gload_lds4(src, &Fs[1 - cur][s]);
        }
      }
    }

    // --- compute chunk ch: per (ci,ky): 4 broadcast Fs b128 + 3 Ws b128
    //     per 144 FMAs; 1728 FMA-instrs per thread per chunk ---
    const float* WsC = Ws[cur];
    const float* FsC = Fs[cur];
    #pragma unroll
    for (int ci = 0; ci < CICH; ++ci) {
      #pragma unroll
      for (int ky = 0; ky < 3; ++ky) {
        const int fb = ci * FREG + ky * 52 + g * PPT;  // all terms %4==0
        float4 f0 = *(const float4*)&FsC[fb];
        float4 f1 = *(const float4*)&FsC[fb + 4];
        float4 f2 = *(const float4*)&FsC[fb + 8];
        float4 f3 = *(const float4*)&FsC[fb + 12];
        float f[16] = {f0.x, f0.y, f0.z, f0.w, f1.x, f1.y, f1.z, f1.w,
                       f2.x, f2.y, f2.z, f2.w, f3.x, f3.y, f3.z, f3.w};
        #pragma unroll
        for (int kx = 0; kx < 3; ++kx) {
          float4 w = *(const float4*)&WsC[(ci * 9 + ky * 3 + kx) * 64 + tp * 4];
          #pragma unroll
          for (int j = 0; j < PPT; ++j) {
            acc[0][j] += w.x * f[j + kx];
            acc[1][j] += w.y * f[j + kx];
            acc[2][j] += w.z * f[j + kx];
            acc[3][j] += w.w * f[j + kx];
          }
        }
      }
    }
    __syncthreads();   // staging loads were issued a full compute body ago
  }

  // --- write partial sums (plain stores) ---
  float* xpz = xp + (size_t)bz * (1024 * NPOS);
  #pragma unroll
  for (int j = 0; j < PPT; ++j) {
    int pl = q0 + g * PPT + j;
    int r = pl / 52, cc = pl - r * 52;
    if (pl < 2704 && r >= 1 && r <= 50 && cc >= 1 && cc <= 50) {
      int p = (r - 1) * 50 + (cc - 1);
      #pragma unroll
      for (int c = 0; c < 4; ++c)
        xpz[(size_t)(co0 + tp * 4 + c) * NPOS + p] = acc[c][j];
    }
  }
}

// ---------------- 1b. reduce partials + bias -------------------------------
__global__ void reducex(const float* __restrict__ xp,
                        const float* __restrict__ b1, float* __restrict__ x) {
  int i = blockIdx.x * 256 + threadIdx.x;
  if (i >= 1024 * NPOS) return;
  const size_t S = (size_t)1024 * NPOS;
  float v = ((xp[i] + xp[i + S]) + (xp[i + 2 * S] + xp[i + 3 * S])) +
            b1[i / NPOS];
  x[i] = v;
}

// ---------------- 2. 1x1 conv heads (36 reg + 18 cls channels) -------------
__global__ __launch_bounds__(256) void heads(
    const float* __restrict__ x, const float* __restrict__ Wreg,
    const float* __restrict__ breg, const float* __restrict__ Wcls,
    const float* __restrict__ bcls, float* __restrict__ ho) {
  int p = blockIdx.x * 64 + threadIdx.x;
  int ch = blockIdx.y * 4 + threadIdx.y;
  if (p >= NPOS || ch >= 54) return;
  const float* w = (ch < 36) ? (Wreg + (size_t)ch * 1024)
                             : (Wcls + (size_t)(ch - 36) * 1024);
  float a0 = 0.f, a1 = 0.f, a2 = 0.f, a3 = 0.f;
  for (int c = 0; c < 1024; c += 4) {
    a0 += w[c + 0] * x[(size_t)(c + 0) * NPOS + p];
    a1 += w[c + 1] * x[(size_t)(c + 1) * NPOS + p];
    a2 += w[c + 2] * x[(size_t)(c + 2) * NPOS + p];
    a3 += w[c + 3] * x[(size_t)(c + 3) * NPOS + p];
  }
  float bias = (ch < 36) ? breg[ch] : bcls[ch - 36];
  ho[p * 56 + ch] = (a0 + a1) + (a2 + a3) + bias;
}

// ---------------- 3. decode + min-size filter + sort keys ------------------
__global__ void decodek(const float* __restrict__ ho,
                        const float* __restrict__ anchors,
                        float4* __restrict__ roi,
                        unsigned long long* __restrict__ keys) {
  int i = blockIdx.x * 256 + threadIdx.x;
  if (i >= NBOX) { keys[i] = 0ull; return; }
  int p = i / 9, a = i % 9;
  const float* hp = ho + p * 56;
  float dy = hp[a * 4 + 0], dx = hp[a * 4 + 1];
  float dh = hp[a * 4 + 2], dw = hp[a * 4 + 3];
  float s = hp[36 + a * 2 + 1];
  float ay1 = anchors[i * 4 + 0], ax1 = anchors[i * 4 + 1];
  float ay2 = anchors[i * 4 + 2], ax2 = anchors[i * 4 + 3];
  float ahh = ay2 - ay1, aww = ax2 - ax1;
  float acy = ay1 + 0.5f * ahh, acx = ax1 + 0.5f * aww;
  float cy = dy * ahh + acy, cx = dx * aww + acx;
  float h = expf(dh) * ahh, w = expf(dw) * aww;
  float y1 = fminf(fmaxf(cy - 0.5f * h, 0.f), 800.f);
  float x1 = fminf(fmaxf(cx - 0.5f * w, 0.f), 800.f);
  float y2 = fminf(fmaxf(cy + 0.5f * h, 0.f), 800.f);
  float x2 = fminf(fmaxf(cx + 0.5f * w, 0.f), 800.f);
  bool valid = ((y2 - y1) >= 16.f) && ((x2 - x1) >= 16.f);
  float sc = valid ? s : -__builtin_inff();
  unsigned u = __float_as_uint(sc);
  u = (u & 0x80000000u) ? ~u : (u | 0x80000000u);
  keys[i] = ((unsigned long long)u << 32) |
            (unsigned long long)(0xFFFFFFFFu - (unsigned)i);
  roi[i] = make_float4(y1, x1, y2, x2);
}

// ---------------- 4. bitonic sort (descending), 32768 keys -----------------
__global__ __launch_bounds__(1024) void bitonic_local(unsigned long long* keys) {
  __shared__ unsigned long long s[4096];
  int t = threadIdx.x;
  size_t base = (size_t)blockIdx.x * 4096;
  for (int m = t; m < 4096; m += 1024) s[m] = keys[base + m];
  __syncthreads();
  for (int k = 2; k <= 4096; k <<= 1) {
    for (int j = k >> 1; j > 0; j >>= 1) {
      for (int m = t; m < 4096; m += 1024) {
        int l = m ^ j;
        if (l > m) {
          bool desc = (((base + (size_t)m) & (size_t)k) == 0);
          unsigned long long a = s[m], b = s[l];
          if (desc ? (a < b) : (a > b)) { s[m] = b; s[l] = a; }
        }
      }
      __syncthreads();
    }
  }
  for (int m = t; m < 4096; m += 1024) keys[base + m] = s[m];
}

__global__ __launch_bounds__(1024) void bitonic_merge_local(
    unsigned long long* keys, int k) {
  __shared__ unsigned long long s[4096];
  int t = threadIdx.x;
  size_t base = (size_t)blockIdx.x * 4096;
  for (int m = t; m < 4096; m += 1024) s[m] = keys[base + m];
  __syncthreads();
  for (int j = 2048; j > 0; j >>= 1) {
    for (int m = t; m < 4096; m += 1024) {
      int l = m ^ j;
      if (l > m) {
        bool desc = (((base + (size_t)m) & (size_t)k) == 0);
        unsigned long long a = s[m], b = s[l];
        if (desc ? (a < b) : (a > b)) { s[m] = b; s[l] = a; }
      }
    }
    __syncthreads();
  }
  for (int m = t; m < 4096; m += 1024) keys[base + m] = s[m];
}

__global__ void bitonic_global(unsigned long long* keys, int k, int j) {
  int m = blockIdx.x * 256 + threadIdx.x;
  int l = m ^ j;
  if (l > m) {
    bool desc = ((m & k) == 0);
    unsigned long long a = keys[m], b = keys[l];
    if (desc ? (a < b) : (a > b)) { keys[m] = b; keys[l] = a; }
  }
}

// ---------------- 5. gather sorted top-6000 boxes + valid flags ------------
__global__ void gatherk(const unsigned long long* __restrict__ keys,
                        const float4* __restrict__ roi,
                        float4* __restrict__ sbox, int* __restrict__ validArr) {
  int t = blockIdx.x * 256 + threadIdx.x;
  if (t >= NPRE) return;
  unsigned long long k = keys[t];
  unsigned u = (unsigned)(k >> 32);
  int valid = (u > 0x007FFFFFu) ? 1 : 0;
  float4 b = make_float4(0.f, 0.f, 0.f, 0.f);
  if (valid) {
    int idx = (int)(0xFFFFFFFFu - (unsigned)(k & 0xFFFFFFFFull));
    b = roi[idx];
  }
  sbox[t] = b;
  validArr[t] = valid;
}

// ---------------- 6. NMS suppression bitmask -------------------------------
__global__ __launch_bounds__(64) void nmsmask(
    const float4* __restrict__ sbox, unsigned long long* __restrict__ mask) {
  int rb = blockIdx.x, cb = blockIdx.y;
  int t = threadIdx.x;
  __shared__ float4 cbx[64];
  __shared__ float car[64];
  int jj = cb * 64 + t;
  float4 c = (jj < NPRE) ? sbox[jj] : make_float4(0.f, 0.f, 0.f, 0.f);
  cbx[t] = c;
  car[t] = (c.w - c.y + 1.f) * (c.z - c.x + 1.f);
  __syncthreads();
  int i = rb * 64 + t;
  if (i >= NPRE) return;
  float4 b = sbox[i];
  float ai = (b.w - b.y + 1.f) * (b.z - b.x + 1.f);
  unsigned long long bits = 0ull;
  int nj = min(64, NPRE - cb * 64);
  for (int j = 0; j < nj; ++j) {
    float4 cc = cbx[j];
    float yy1 = fmaxf(b.x, cc.x), xx1 = fmaxf(b.y, cc.y);
    float yy2 = fminf(b.z, cc.z), xx2 = fminf(b.w, cc.w);
    float inter = fmaxf(xx2 - xx1 + 1.f, 0.f) * fmaxf(yy2 - yy1 + 1.f, 0.f);
    float iou = inter / (ai + car[j] - inter);
    if (iou > 0.7f) bits |= (1ull << j);
  }
  mask[(size_t)i * NWORDS + cb] = bits;
}

// ---------------- 7. greedy scan (single wave) + output --------------------
__global__ __launch_bounds__(64) void nmsscan(
    const unsigned long long* __restrict__ mask,
    const int* __restrict__ validArr, const float4* __restrict__ sbox,
    float* __restrict__ out) {
  int t = threadIdx.x;
  __shared__ unsigned long long remv[NWORDS];
  __shared__ int keepIdx[NPOST];
  remv[t] = 0ull;
  if (t + 64 < NWORDS) remv[t + 64] = 0ull;
  __syncthreads();
  int nk = 0;
  for (int wb = 0; wb < NWORDS && nk < NPOST; ++wb) {
    int gi = wb * 64 + t;
    bool v = (gi < NPRE) && (validArr[gi] != 0);
    unsigned long long avail = __ballot(v);
    avail &= ~remv[wb];
    while (avail != 0ull && nk < NPOST) {
      int b = __ffsll((unsigned long long)avail) - 1;
      int i = wb * 64 + b;
      if (t == 0) keepIdx[nk] = i;
      nk++;
      const unsigned long long* row = mask + (size_t)i * NWORDS;
      remv[t] |= row[t];
      if (t + 64 < NWORDS) remv[t + 64] |= row[t + 64];
      __syncthreads();
      avail &= ~remv[wb];
    }
  }
  __syncthreads();
  for (int r = t; r < NPOST; r += 64) {
    float4 bx = make_float4(0.f, 0.f, 0.f, 0.f);
    if (r < nk) bx = sbox[keepIdx[r]];
    reinterpret_cast<float4*>(out)[r] = bx;
  }
}

// ---------------------------------------------------------------------------
extern "C" void kernel_launch(void* const* d_in, const int* in_sizes, int n_in,
                              void* d_out, int out_size, void* d_ws,
                              size_t ws_size, hipStream_t stream) {
  const float* feat    = (const float*)d_in[0];
  const float* anchors = (const float*)d_in[1];
  const float* W1      = (const float*)d_in[2];
  const float* b1      = (const float*)d_in[3];
  const float* Wreg    = (const float*)d_in[4];
  const float* breg    = (const float*)d_in[5];
  const float* Wcls    = (const float*)d_in[6];
  const float* bcls    = (const float*)d_in[7];

  char* ws = (char*)d_ws;
  float* x                 = (float*)(ws);             // 10,240,000 B
  float* xp                = (float*)(ws + 10240000);  // 40,960,000 B (dead after reducex)
  // aliases inside xp (written strictly after reducex):
  float4* sbox             = (float4*)(ws + 10240000);          //     96,256 B
  int* validArr            = (int*)(ws + 10336256);             //     24,064 B
  unsigned long long* mask = (unsigned long long*)(ws + 10360320); // 4,524,032 B
  float* ho                = (float*)(ws + 51200000);  //    560,000 B
  float4* roi              = (float4*)(ws + 51760000); //    360,000 B
  unsigned long long* keys = (unsigned long long*)(ws + 52120000); // 262,144 B
  // zero source for conv feature padding: aliases keys[0..15] (keys is dead
  // during conv; decodek rewrites it afterwards, same order every launch)
  float* zerop             = (float*)(ws + 52120000);
  float* Wt                = (float*)(ws + 52382144);  // 75,497,472 B (transposed W1)
  float* out = (float*)d_out;

  initzero<<<1, 64, 0, stream>>>(zerop);
  transposeW<<<dim3(288, 16), 256, 0, stream>>>(W1, Wt);
  conv3x3_v8<<<dim3(NPT, 16, KSPLIT), 256, 0, stream>>>(feat, Wt, xp, zerop);
  reducex<<<10000, 256, 0, stream>>>(xp, b1, x);
  heads<<<dim3(40, 14), dim3(64, 4), 0, stream>>>(x, Wreg, breg, Wcls, bcls, ho);
  decodek<<<128, 256, 0, stream>>>(ho, anchors, roi, keys);

  bitonic_local<<<8, 1024, 0, stream>>>(keys);
  for (int k = 8192; k <= NSORT; k <<= 1) {
    for (int j = k >> 1; j >= 4096; j >>= 1)
      bitonic_global<<<128, 256, 0, stream>>>(keys, k, j);
    bitonic_merge_local<<<8, 1024, 0, stream>>>(keys, k);
  }

  gatherk<<<24, 256, 0, stream>>>(keys, roi, sbox, validArr);
  nmsmask<<<dim3(NWORDS, NWORDS), 64, 0, stream>>>(sbox, mask);
  nmsscan<<<1, 64, 0, stream>>>(mask, validArr, sbox, out);
}